// Round 2
// baseline (632.828 us; speedup 1.0000x reference)
//
#include <hip/hip_runtime.h>

// Problem constants (B=2,H=16,S=2048,D=128 — fixed by the reference).
#define S 2048
#define D 128
#define BH 32
#define ROWS (BH * S)  // 65536 rows per tensor

typedef __bf16 bf16x8 __attribute__((ext_vector_type(8)));
typedef float f32x4 __attribute__((ext_vector_type(4)));
typedef __attribute__((address_space(1))) unsigned int GU;
typedef __attribute__((address_space(3))) unsigned int LU;

__device__ __forceinline__ unsigned short f2bf(float f) {
  // round-to-nearest-even fp32 -> bf16 (finite inputs only)
  unsigned u = __float_as_uint(f);
  u += 0x7fffu + ((u >> 16) & 1u);
  return (unsigned short)(u >> 16);
}

__device__ __forceinline__ void ld_g2l16(const unsigned short* g, unsigned short* l) {
  // async 16B global->LDS; LDS dest must be wave-uniform base + lane*16
  __builtin_amdgcn_global_load_lds((const GU*)g, (LU*)l, 16, 0, 0);
}

// ---- Pass 1: L2-normalize each 128-elem row, emit bf16 -------------------
__global__ __launch_bounds__(256) void normalize_rows(
    const float* __restrict__ x, unsigned short* __restrict__ y) {
  const int wave = threadIdx.x >> 6;
  const int lane = threadIdx.x & 63;
  const int row = (blockIdx.x << 2) + wave;
  const float2 v = ((const float2*)(x + (size_t)row * D))[lane];
  float ss = v.x * v.x + v.y * v.y;
#pragma unroll
  for (int m = 32; m; m >>= 1) ss += __shfl_xor(ss, m, 64);
  const float scale = 1.0f / fmaxf(sqrtf(ss), 1e-12f);
  const unsigned lo = f2bf(v.x * scale);
  const unsigned hi = f2bf(v.y * scale);
  ((unsigned int*)(y + (size_t)row * D))[lane] = lo | (hi << 16);
}

// ---- Pass 2: C = exp(clamp((Qn·Knᵀ)/temp)) + 1e-6 ------------------------
// Compute structure identical to v1 (K-tile in LDS, Q direct from global,
// wave owns a 32x128 output strip). CHANGED: the epilogue. Instead of 64
// scalar dword stores/thread (4x64B segments per wave-store), each wave
// transposes its exp'd accumulators through a private 16KB LDS region and
// stores 2 full output rows (2x512B contiguous) per global_store_dwordx4:
// 16 store instrs/wave, 8x longer contiguous runs.
__global__ __launch_bounds__(256, 2) void qk_exp_kernel(
    const unsigned short* __restrict__ Qn, const unsigned short* __restrict__ Kn,
    const float* __restrict__ logt, float* __restrict__ out) {
  // 64KB: first 32KB stages K (bf16); after MFMA the whole buffer becomes
  // 4 per-wave 16KB f32 transpose regions.
  __shared__ __align__(16) float smemT[16384];
  unsigned short* lK = (unsigned short*)smemT;

  const int tid = threadIdx.x;
  const int nt_ = blockIdx.x, mt_ = blockIdx.y, bh = blockIdx.z;
  const unsigned short* Qb = Qn + ((size_t)bh * S + (size_t)mt_ * 128) * D;
  const unsigned short* Kb = Kn + ((size_t)bh * S + (size_t)nt_ * 128) * D;

  // Stage K tile: 2048 16B-chunks, 8 per thread. XOR swizzle applied on the
  // GLOBAL side (global_load_lds dest must be linear), inverse applied on
  // the LDS fragment read below.
#pragma unroll
  for (int it = 0; it < 8; ++it) {
    const int L = (it << 8) + tid;             // 16B-chunk index in LDS
    const int r = L >> 4, c = L & 15;          // row (256B), chunk-in-row
    const int g = (r << 4) + (c ^ (r & 15));   // swizzled global chunk
    ld_g2l16(Kb + (g << 3), lK + (L << 3));
  }

  const int lane = tid & 63, wave = tid >> 6;
  const int wr = wave << 5;  // wave owns output rows wr..wr+31 (x all 128 cols)
  const int lm = lane & 15, kq = lane >> 4;

  // Q fragment base for this lane: row (wr+lm), k-offset kq*8 elems.
  const unsigned short* qrow0 = Qb + (size_t)(wr + lm) * D + (kq << 3);

  // Prefetch ks=0 Q fragments BEFORE the barrier — the barrier's vmcnt(0)
  // drain covers both the staging and these, so the latency overlaps.
  bf16x8 a0 = *(const bf16x8*)(qrow0);
  bf16x8 a1 = *(const bf16x8*)(qrow0 + (D << 4));
  __syncthreads();  // staging complete

  f32x4 acc[2][8] = {};
#pragma unroll
  for (int ks = 0; ks < 4; ++ks) {
    // software-pipeline next ks's Q fragments (ks=3 reloads ks=0: L1-hit)
    const int ksn = (ks + 1) & 3;
    bf16x8 a0n = *(const bf16x8*)(qrow0 + (ksn << 5));
    bf16x8 a1n = *(const bf16x8*)(qrow0 + (D << 4) + (ksn << 5));

    const int kc = (ks << 2) + kq;       // 16B k-chunk (0..15)
    const int sw = (kc ^ lm) << 3;       // inverse-swizzled k-offset (elems)
    bf16x8 b[8];
#pragma unroll
    for (int nt = 0; nt < 8; ++nt)
      b[nt] = *(const bf16x8*)(lK + ((nt << 4) + lm) * D + sw);
#pragma unroll
    for (int nt = 0; nt < 8; ++nt) {
      acc[0][nt] = __builtin_amdgcn_mfma_f32_16x16x32_bf16(a0, b[nt], acc[0][nt], 0, 0, 0);
      acc[1][nt] = __builtin_amdgcn_mfma_f32_16x16x32_bf16(a1, b[nt], acc[1][nt], 0, 0, 0);
    }
    a0 = a0n;
    a1 = a1n;
  }

  __syncthreads();  // all waves done reading lK -> reuse as transpose buffers

  float temp = __expf(logt[0]);
  temp = fminf(fmaxf(temp, 0.05f), 100.0f);
  const float invt = 1.0f / temp;

  // ---- Epilogue: exp + per-wave LDS transpose + contiguous dwordx4 stores.
  // Wave-private region: 32 rows x 128 f32 = 16KB. XOR swizzle
  // col' = col ^ (((row>>1)&7)<<2) keeps ds_write2 pairing (rows r,r+1
  // share the swizzle for even r) and spreads the kq row-groups across
  // bank halves (<=2-way on write = free; read at b128 inherent minimum).
  float* tw = smemT + (wave << 12);
#pragma unroll
  for (int mt = 0; mt < 2; ++mt) {
#pragma unroll
    for (int nt = 0; nt < 8; ++nt) {
      const int c = (nt << 4) + lm;
#pragma unroll
      for (int rp = 0; rp < 2; ++rp) {
        const int lr = (mt << 4) + (kq << 2) + (rp << 1);  // even
        const int X = ((lr >> 1) & 7) << 2;
        const int idx = (lr << 7) + (c ^ X);
        float s0 = acc[mt][nt][rp * 2 + 0] * invt;
        float s1 = acc[mt][nt][rp * 2 + 1] * invt;
        s0 = fminf(fmaxf(s0, -100.0f), 100.0f);
        s1 = fminf(fmaxf(s1, -100.0f), 100.0f);
        tw[idx] = __expf(s0) + 1e-6f;        // row lr
        tw[idx + 128] = __expf(s1) + 1e-6f;  // row lr+1 (same X)
      }
    }
  }
  // No cross-wave barrier needed: each wave reads only its own region and
  // DS ops are in-order within a wave.

  float* Cb = out + ((size_t)bh << 22);  // bh * S * S
  const int l5 = lane >> 5, l31 = lane & 31;
  const size_t gbase =
      (size_t)((mt_ << 7) + wr) * S + (nt_ << 7) + (l31 << 2);
#pragma unroll
  for (int rr = 0; rr < 16; ++rr) {
    const int lr = (rr << 1) + l5;          // row within strip
    const int X = (rr & 7) << 2;            // == ((lr>>1)&7)<<2
    const f32x4 v = *(const f32x4*)(tw + (lr << 7) + (((l31 << 2)) ^ X));
    *(f32x4*)(Cb + gbase + (size_t)lr * S) = v;  // 2 rows x 512B per instr
  }
}

extern "C" void kernel_launch(void* const* d_in, const int* in_sizes, int n_in,
                              void* d_out, int out_size, void* d_ws, size_t ws_size,
                              hipStream_t stream) {
  const float* q = (const float*)d_in[0];
  const float* k = (const float*)d_in[1];
  const float* lt = (const float*)d_in[2];
  float* out = (float*)d_out;
  unsigned short* qn = (unsigned short*)d_ws;               // 16.78 MB
  unsigned short* kn = qn + (size_t)ROWS * D;               // 16.78 MB
  normalize_rows<<<ROWS / 4, 256, 0, stream>>>(q, qn);
  normalize_rows<<<ROWS / 4, 256, 0, stream>>>(k, kn);
  dim3 grid(S / 128, S / 128, BH);
  qk_exp_kernel<<<grid, 256, 0, stream>>>(qn, kn, lt, out);
}